// Round 6
// baseline (334.682 us; speedup 1.0000x reference)
//
#include <hip/hip_runtime.h>
#include <hip/hip_bf16.h>

// GLinear: out[p,o,d] = W_{seg(d)}[o,i] * x[p,i,d] + x[p,o,d]
// P=8192, C=256, D=16. seg: d=0->W00, 1..6->W10, 7..15->W11.
// R10. R9 post-mortem: per-chunk cost is invariant at ~18.7k cy for a 64KB
// chunk whose stream floor is 6.4k cy -> per-CU memory-concurrency limit
// (1 block = 64 outstanding glds can't stream full rate; serial
// vmcnt->pack->barrier chain stalls the whole CU). Fix = TLP: 2 blocks/CU.
//  - KC 32: scratch 32KB + tile dbuf 2x20KB => LDS 73728 B -> 2 blocks/CU
//  - W preload (96 VGPR) -> per-chunk reload of 3 frags, prefetched 1 chunk
//    ahead from packed ws (L2-resident); only ever waited by the pack-top
//    vmcnt(0) that already exists
//  - launch_bounds(512,4): <=128 regs -> 16 waves/CU
//  - tile rows indexed d*16+p, LDS_ROW=40 (16B-mult): compute ds_read_b128
//    is exactly 8-phase bank-conflict-free (lm*20 + g*4 covers all 8 slots)
//  - sync per chunk (vmcnt(0) + one __syncthreads) identical to verified R9

#define C_DIM   256
#define D_DIM   16
#define P_TILE  16
#define KC      32
#define NCH     8      // chunks per C (256/32)
#define LDS_ROW 40     // bf16 elems per tile row: 32 data + 8 pad
#define UNITS   2      // p-tiles per block
#define NFRAG   (2 * 8 * 24 * 64)   // (oh, w, frag, lane) fragment-lanes
#define WS_NEEDED (NFRAG * 16)      // 393216 B

typedef __attribute__((ext_vector_type(8))) short  short8v;
typedef __attribute__((ext_vector_type(4))) float  float4v;
typedef __attribute__((ext_vector_type(4))) unsigned int uint4v;

// RNE fp32->bf16 pair pack
__device__ __forceinline__ unsigned int pack_bf16x2_rne(float lo, float hi) {
    unsigned int ul = __builtin_bit_cast(unsigned int, lo);
    unsigned int uh = __builtin_bit_cast(unsigned int, hi);
    ul = (ul + 0x7fffu + ((ul >> 16) & 1u)) >> 16;
    uh = (uh + 0x7fffu + ((uh >> 16) & 1u));
    return (ul & 0xffffu) | (uh & 0xffff0000u);
}

// Truncating pack (fallback W path only; error budget has 2.8x margin)
__device__ __forceinline__ unsigned int pack_bf16x2_tr(float lo, float hi) {
    return __builtin_amdgcn_perm(__builtin_bit_cast(unsigned int, hi),
                                 __builtin_bit_cast(unsigned int, lo),
                                 0x07060302u);
}

__device__ __forceinline__ short8v load_w_frag(const float* __restrict__ W, int row, int col) {
    const float* p = W + (size_t)row * C_DIM + col;
    float4v a = *(const float4v*)p;
    float4v b = *(const float4v*)(p + 4);
    uint4v u;
    u.x = pack_bf16x2_tr(a.x, a.y);
    u.y = pack_bf16x2_tr(a.z, a.w);
    u.z = pack_bf16x2_tr(b.x, b.y);
    u.w = pack_bf16x2_tr(b.z, b.w);
    return __builtin_bit_cast(short8v, u);
}

// async 16B global -> LDS (dest is wave-uniform base + lane*16)
__device__ __forceinline__ void glds16(const float* g, float* l) {
    __builtin_amdgcn_global_load_lds(
        (const __attribute__((address_space(1))) void*)g,
        (__attribute__((address_space(3))) void*)l,
        16, 0, 0);
}

// ---- init: pack W into per-wave-contiguous bf16 fragments in workspace ----
// layout: frag (oh, w, f=ic64*6+ks*3+mat), lane l -> 16B at
//   ws[(((oh*8 + w)*24 + f)*64 + l) * 16B]
// lane l holds cols [ic64*64+ks*32+(l>>4)*8, +8) of row oh*128+w*16+(l&15).
__global__ __launch_bounds__(256, 4) void init_w_pack(
    const float* __restrict__ W00, const float* __restrict__ W10,
    const float* __restrict__ W11, uint4v* __restrict__ ws)
{
    const int tid = blockIdx.x * 256 + threadIdx.x;     // 24576 threads
    if (tid >= NFRAG) return;
    const int l   = tid & 63;
    int idx = tid >> 6;
    const int f  = idx % 24;
    idx /= 24;
    const int w  = idx & 7;
    const int oh = idx >> 3;
    const int mat = f % 3;
    const int ks  = (f / 3) & 1;
    const int ic  = f / 6;
    const float* Wm = (mat == 0) ? W00 : (mat == 1) ? W10 : W11;
    const int row = oh * 128 + w * 16 + (l & 15);
    const int col = ic * 64 + ks * 32 + (l >> 4) * 8;
    const float* p = Wm + (size_t)row * C_DIM + col;
    float4v a = *(const float4v*)p;
    float4v b = *(const float4v*)(p + 4);
    uint4v u;
    u.x = pack_bf16x2_rne(a.x, a.y);
    u.y = pack_bf16x2_rne(a.z, a.w);
    u.z = pack_bf16x2_rne(b.x, b.y);
    u.w = pack_bf16x2_rne(b.z, b.w);
    ws[tid] = u;
}

__global__ __launch_bounds__(512, 4) void glinear_kernel(
    const float* __restrict__ x, const float* __restrict__ W00,
    const float* __restrict__ W10, const float* __restrict__ W11,
    float* __restrict__ out, const short8v* __restrict__ wpack, int use_ws)
{
    // fp32 staging scratch: 32 regions of 1 KiB; region (w, j) is written by
    // wave w's glds and read ONLY by wave w -> wave-private, no barrier.
    __shared__ __align__(16) float f32s[32 * 256];                      // 32768 B
    // bf16 x-tile, double-buffered: elem (p,i,d) at row d*16+p,
    // col = ((iloc>>3)^(p&3))*8 + (iloc&7), iloc chunk-local (0..31)
    __shared__ __align__(16) unsigned short ls[2][256 * LDS_ROW];       // 40960 B

    const int t    = threadIdx.x;
    const int lane = t & 63;
    const int w    = t >> 6;          // wave 0..7 -> 16 o-cols each
    const int lm   = lane & 15;
    const int quad = lane >> 4;
    const int d4   = lane & 3;        // d-group of 4
    const int ip   = (lane >> 2) & 15;// i-pair index (chunk-local)

    const int oh    = blockIdx.x & 1;
    const int pg    = blockIdx.x >> 1;        // 0..255, 2 p-tiles each
    const int obase = oh * 128 + w * 16;
    const int orow  = obase + lm;

    const short8v* wbase = wpack + ((size_t)(oh * 8 + w) * 24) * 64 + lane;

    // W fragments for chunk c: 3 (W00, W10, W11); prefetched 1 chunk ahead.
    short8v wf[NCH][3];
    auto loadW = [&](int c) {
        if (use_ws) {
            #pragma unroll
            for (int mat = 0; mat < 3; ++mat)
                wf[c][mat] = wbase[(size_t)((c >> 1) * 6 + (c & 1) * 3 + mat) * 64];
        } else {
            const int col = (c >> 1) * 64 + (c & 1) * 32 + quad * 8;
            wf[c][0] = load_w_frag(W00, orow, col);
            wf[c][1] = load_w_frag(W10, orow, col);
            wf[c][2] = load_w_frag(W11, orow, col);
        }
    };

    // ---- async stage of one 32-i chunk (32 KB) into wave-private scratch ----
    // wave w covers p in {w, w+8}; glds j: p = w+(j>>1)*8, i parity j&1.
    // lane l -> i = c*32 + 2*ip + parity, d = d4*4..+4 (16B contiguous).
    auto stage_chunk = [&](int pb, int c) {
        #pragma unroll
        for (int j = 0; j < 4; ++j) {
            const int p = w + (j >> 1) * 8;
            const int i = c * KC + ip * 2 + (j & 1);
            const float* src = x + ((size_t)(pb + p) * C_DIM + i) * D_DIM + d4 * 4;
            glds16(src, &f32s[(w * 4 + j) << 8]);
        }
    };

    loadW(0);                               // W(0): issued before glds(0)
    stage_chunk(pg * UNITS * P_TILE, 0);    // prologue: unit 0, chunk 0

    for (int u = 0; u < UNITS; ++u) {
        const int pbase = (pg * UNITS + u) * P_TILE;

        float4v acc[16];
        const float4v fzero = {0.f, 0.f, 0.f, 0.f};
        #pragma unroll
        for (int b = 0; b < 16; ++b) acc[b] = fzero;

        #pragma unroll
        for (int c = 0; c < NCH; ++c) {
            const int ib = c & 1;

            // wait own glds (+ this chunk's W, issued just before it)
            asm volatile("s_waitcnt vmcnt(0)" ::: "memory");

            // ---- pack: scratch fp32 -> bf16 tile ls[ib] ----
            #pragma unroll
            for (int m = 0; m < 2; ++m) {
                const int p = w + m * 8;
                float4v a = *(const float4v*)&f32s[((w * 4 + m * 2 + 0) << 8) + lane * 4];
                float4v b = *(const float4v*)&f32s[((w * 4 + m * 2 + 1) << 8) + lane * 4];
                const int cb = (((ip >> 2) ^ (p & 3)) * 8 + (ip & 3) * 2);
                #pragma unroll
                for (int dj = 0; dj < 4; ++dj) {
                    const int row = (d4 * 4 + dj) * 16 + p;
                    *(unsigned int*)&ls[ib][row * LDS_ROW + cb] = pack_bf16x2_rne(a[dj], b[dj]);
                }
            }
            // implicit vmcnt(0) drain hits an empty queue (waited above)
            __syncthreads();

            // ---- prefetch next chunk's W then x (W older -> never drains glds)
            const bool last = (u == UNITS - 1) && (c == NCH - 1);
            if (!last) {
                const int nc = (c + 1) & (NCH - 1);
                loadW(nc);
                stage_chunk((c == NCH - 1) ? pbase + P_TILE : pbase, nc);
            }
            asm volatile("" ::: "memory");   // pin: prefetch issue precedes compute

            // ---- compute: 16 MFMA (one K=32 step), pure ds_read + reg W ----
            #pragma unroll
            for (int dd = 0; dd < 16; ++dd) {
                const int row = dd * 16 + lm;
                const int gq  = quad ^ (lm & 3);
                short8v xf = *(const short8v*)&ls[ib][row * LDS_ROW + gq * 8];
                short8v wv = (dd == 0) ? wf[c][0] : (dd <= 6) ? wf[c][1] : wf[c][2];
                // A = x (m=p), B = W (n=o) -> D row=p(quad*4+reg), col=o(lm)
                acc[dd] = __builtin_amdgcn_mfma_f32_16x16x32_bf16(xf, wv, acc[dd], 0, 0, 0);
            }
        }

        // ---- epilogue: plain stores; residual x re-read is an L2/L3 hit ----
        #pragma unroll
        for (int r = 0; r < 4; ++r) {
            const int p = pbase + quad * 4 + r;
            const int o = obase + lm;
            const size_t off = (size_t)p * (C_DIM * D_DIM) + (size_t)o * D_DIM;
            #pragma unroll
            for (int g = 0; g < 4; ++g) {
                float4v v;
                v.x = acc[g * 4 + 0][r];
                v.y = acc[g * 4 + 1][r];
                v.z = acc[g * 4 + 2][r];
                v.w = acc[g * 4 + 3][r];
                float4v xr = *(const float4v*)(x + off + g * 4);
                *(float4v*)(out + off + g * 4) = v + xr;
            }
        }
    }
}

extern "C" void kernel_launch(void* const* d_in, const int* in_sizes, int n_in,
                              void* d_out, int out_size, void* d_ws, size_t ws_size,
                              hipStream_t stream) {
    const float* x   = (const float*)d_in[0];
    const float* W00 = (const float*)d_in[1];
    const float* W10 = (const float*)d_in[2];
    const float* W11 = (const float*)d_in[3];
    float* out = (float*)d_out;

    const int use_ws = (d_ws != nullptr && ws_size >= WS_NEEDED) ? 1 : 0;
    if (use_ws) {
        hipLaunchKernelGGL(init_w_pack, dim3(96), dim3(256), 0, stream,
                           W00, W10, W11, (uint4v*)d_ws);
    }
    // grid 512: 2 blocks/CU (LDS 73728 B, <=128 regs). (bid>>1)=p-group of
    // 2 tiles, (bid&1)=o-half; adjacent pair shares x reads through L2/L3.
    hipLaunchKernelGGL(glinear_kernel, dim3(512), dim3(512), 0, stream,
                       x, W00, W10, W11, out, (const short8v*)d_ws, use_ws);
}

// Round 7
// 326.341 us; speedup vs baseline: 1.0256x; 1.0256x over previous
//
#include <hip/hip_runtime.h>
#include <hip/hip_bf16.h>

// GLinear: out[p,o,d] = W_{seg(d)}[o,i] * x[p,i,d] + x[p,o,d]
// P=8192, C=256, D=16. seg: d=0->W00, 1..6->W10, 7..15->W11.
// R11. R10 post-mortem: 2 blocks/CU worked (occ 40%, BW 3.0 TB/s) but
// traffic exploded symmetrically (FETCH +87, WRITE +89 MB):
//  (1) oh=bid&1 put x-tile-sharing pairs on DIFFERENT XCDs -> x fetched
//      into two L2s; L3 thrashed by out stream -> 2nd fetch = HBM. x read 2x.
//  (2) epilogue 64B lines assembled by 4x16B stores with a ~900cy residual
//      load interleaved -> lines evicted half-dirty under 16-wave churn ->
//      partial writeback + RFO refetch (symmetric +FETCH/+WRITE).
// Fixes:
//  - oh = bid>>8, pg = bid&255: pair (pg,0)/(pg,1) = bids b,b+256 -> same
//    XCD/CU slot -> 2nd block's glds hits L2; x HBM-fetched once.
//  - epilogue: 4 residual loads FIRST, then 4 back-to-back stores per row
//    -> 64B line completes immediately, eviction window closed.
// Unchanged (verified R10, absmax 0.03125): KC=32 pipeline, scratch glds
// staging, RNE pack, swizzled dbuf tile, per-chunk W reload from packed ws,
// launch_bounds(512,4), one vmcnt(0)+__syncthreads per chunk.

#define C_DIM   256
#define D_DIM   16
#define P_TILE  16
#define KC      32
#define NCH     8      // chunks per C (256/32)
#define LDS_ROW 40     // bf16 elems per tile row: 32 data + 8 pad
#define UNITS   2      // p-tiles per block
#define NFRAG   (2 * 8 * 24 * 64)   // (oh, w, frag, lane) fragment-lanes
#define WS_NEEDED (NFRAG * 16)      // 393216 B

typedef __attribute__((ext_vector_type(8))) short  short8v;
typedef __attribute__((ext_vector_type(4))) float  float4v;
typedef __attribute__((ext_vector_type(4))) unsigned int uint4v;

// RNE fp32->bf16 pair pack
__device__ __forceinline__ unsigned int pack_bf16x2_rne(float lo, float hi) {
    unsigned int ul = __builtin_bit_cast(unsigned int, lo);
    unsigned int uh = __builtin_bit_cast(unsigned int, hi);
    ul = (ul + 0x7fffu + ((ul >> 16) & 1u)) >> 16;
    uh = (uh + 0x7fffu + ((uh >> 16) & 1u));
    return (ul & 0xffffu) | (uh & 0xffff0000u);
}

// Truncating pack (fallback W path only; error budget has 2.8x margin)
__device__ __forceinline__ unsigned int pack_bf16x2_tr(float lo, float hi) {
    return __builtin_amdgcn_perm(__builtin_bit_cast(unsigned int, hi),
                                 __builtin_bit_cast(unsigned int, lo),
                                 0x07060302u);
}

__device__ __forceinline__ short8v load_w_frag(const float* __restrict__ W, int row, int col) {
    const float* p = W + (size_t)row * C_DIM + col;
    float4v a = *(const float4v*)p;
    float4v b = *(const float4v*)(p + 4);
    uint4v u;
    u.x = pack_bf16x2_tr(a.x, a.y);
    u.y = pack_bf16x2_tr(a.z, a.w);
    u.z = pack_bf16x2_tr(b.x, b.y);
    u.w = pack_bf16x2_tr(b.z, b.w);
    return __builtin_bit_cast(short8v, u);
}

// async 16B global -> LDS (dest is wave-uniform base + lane*16)
__device__ __forceinline__ void glds16(const float* g, float* l) {
    __builtin_amdgcn_global_load_lds(
        (const __attribute__((address_space(1))) void*)g,
        (__attribute__((address_space(3))) void*)l,
        16, 0, 0);
}

// ---- init: pack W into per-wave-contiguous bf16 fragments in workspace ----
// layout: frag (oh, w, f=ic64*6+ks*3+mat), lane l -> 16B at
//   ws[(((oh*8 + w)*24 + f)*64 + l) * 16B]
// lane l holds cols [ic64*64+ks*32+(l>>4)*8, +8) of row oh*128+w*16+(l&15).
__global__ __launch_bounds__(256, 4) void init_w_pack(
    const float* __restrict__ W00, const float* __restrict__ W10,
    const float* __restrict__ W11, uint4v* __restrict__ ws)
{
    const int tid = blockIdx.x * 256 + threadIdx.x;     // 24576 threads
    if (tid >= NFRAG) return;
    const int l   = tid & 63;
    int idx = tid >> 6;
    const int f  = idx % 24;
    idx /= 24;
    const int w  = idx & 7;
    const int oh = idx >> 3;
    const int mat = f % 3;
    const int ks  = (f / 3) & 1;
    const int ic  = f / 6;
    const float* Wm = (mat == 0) ? W00 : (mat == 1) ? W10 : W11;
    const int row = oh * 128 + w * 16 + (l & 15);
    const int col = ic * 64 + ks * 32 + (l >> 4) * 8;
    const float* p = Wm + (size_t)row * C_DIM + col;
    float4v a = *(const float4v*)p;
    float4v b = *(const float4v*)(p + 4);
    uint4v u;
    u.x = pack_bf16x2_rne(a.x, a.y);
    u.y = pack_bf16x2_rne(a.z, a.w);
    u.z = pack_bf16x2_rne(b.x, b.y);
    u.w = pack_bf16x2_rne(b.z, b.w);
    ws[tid] = u;
}

__global__ __launch_bounds__(512, 4) void glinear_kernel(
    const float* __restrict__ x, const float* __restrict__ W00,
    const float* __restrict__ W10, const float* __restrict__ W11,
    float* __restrict__ out, const short8v* __restrict__ wpack, int use_ws)
{
    // fp32 staging scratch: 32 regions of 1 KiB; region (w, j) is written by
    // wave w's glds and read ONLY by wave w -> wave-private, no barrier.
    __shared__ __align__(16) float f32s[32 * 256];                      // 32768 B
    // bf16 x-tile, double-buffered: elem (p,i,d) at row d*16+p,
    // col = ((iloc>>3)^(p&3))*8 + (iloc&7), iloc chunk-local (0..31)
    __shared__ __align__(16) unsigned short ls[2][256 * LDS_ROW];       // 40960 B

    const int t    = threadIdx.x;
    const int lane = t & 63;
    const int w    = t >> 6;          // wave 0..7 -> 16 o-cols each
    const int lm   = lane & 15;
    const int quad = lane >> 4;
    const int d4   = lane & 3;        // d-group of 4
    const int ip   = (lane >> 2) & 15;// i-pair index (chunk-local)

    // pair co-location: (pg, oh=0/1) = bids b and b+256 -> same XCD & CU slot
    const int oh    = blockIdx.x >> 8;
    const int pg    = blockIdx.x & 255;       // 0..255, 2 p-tiles each
    const int obase = oh * 128 + w * 16;
    const int orow  = obase + lm;

    const short8v* wbase = wpack + ((size_t)(oh * 8 + w) * 24) * 64 + lane;

    // W fragments for chunk c: 3 (W00, W10, W11); prefetched 1 chunk ahead.
    short8v wf[NCH][3];
    auto loadW = [&](int c) {
        if (use_ws) {
            #pragma unroll
            for (int mat = 0; mat < 3; ++mat)
                wf[c][mat] = wbase[(size_t)((c >> 1) * 6 + (c & 1) * 3 + mat) * 64];
        } else {
            const int col = (c >> 1) * 64 + (c & 1) * 32 + quad * 8;
            wf[c][0] = load_w_frag(W00, orow, col);
            wf[c][1] = load_w_frag(W10, orow, col);
            wf[c][2] = load_w_frag(W11, orow, col);
        }
    };

    // ---- async stage of one 32-i chunk (32 KB) into wave-private scratch ----
    // wave w covers p in {w, w+8}; glds j: p = w+(j>>1)*8, i parity j&1.
    // lane l -> i = c*32 + 2*ip + parity, d = d4*4..+4 (16B contiguous).
    auto stage_chunk = [&](int pb, int c) {
        #pragma unroll
        for (int j = 0; j < 4; ++j) {
            const int p = w + (j >> 1) * 8;
            const int i = c * KC + ip * 2 + (j & 1);
            const float* src = x + ((size_t)(pb + p) * C_DIM + i) * D_DIM + d4 * 4;
            glds16(src, &f32s[(w * 4 + j) << 8]);
        }
    };

    loadW(0);                               // W(0): issued before glds(0)
    stage_chunk(pg * UNITS * P_TILE, 0);    // prologue: unit 0, chunk 0

    for (int u = 0; u < UNITS; ++u) {
        const int pbase = (pg * UNITS + u) * P_TILE;

        float4v acc[16];
        const float4v fzero = {0.f, 0.f, 0.f, 0.f};
        #pragma unroll
        for (int b = 0; b < 16; ++b) acc[b] = fzero;

        #pragma unroll
        for (int c = 0; c < NCH; ++c) {
            const int ib = c & 1;

            // wait own glds (+ this chunk's W, issued just before it)
            asm volatile("s_waitcnt vmcnt(0)" ::: "memory");

            // ---- pack: scratch fp32 -> bf16 tile ls[ib] ----
            #pragma unroll
            for (int m = 0; m < 2; ++m) {
                const int p = w + m * 8;
                float4v a = *(const float4v*)&f32s[((w * 4 + m * 2 + 0) << 8) + lane * 4];
                float4v b = *(const float4v*)&f32s[((w * 4 + m * 2 + 1) << 8) + lane * 4];
                const int cb = (((ip >> 2) ^ (p & 3)) * 8 + (ip & 3) * 2);
                #pragma unroll
                for (int dj = 0; dj < 4; ++dj) {
                    const int row = (d4 * 4 + dj) * 16 + p;
                    *(unsigned int*)&ls[ib][row * LDS_ROW + cb] = pack_bf16x2_rne(a[dj], b[dj]);
                }
            }
            // implicit vmcnt(0) drain hits an empty queue (waited above)
            __syncthreads();

            // ---- prefetch next chunk's W then x (W older -> never drains glds)
            const bool last = (u == UNITS - 1) && (c == NCH - 1);
            if (!last) {
                const int nc = (c + 1) & (NCH - 1);
                loadW(nc);
                stage_chunk((c == NCH - 1) ? pbase + P_TILE : pbase, nc);
            }
            asm volatile("" ::: "memory");   // pin: prefetch issue precedes compute

            // ---- compute: 16 MFMA (one K=32 step), pure ds_read + reg W ----
            #pragma unroll
            for (int dd = 0; dd < 16; ++dd) {
                const int row = dd * 16 + lm;
                const int gq  = quad ^ (lm & 3);
                short8v xf = *(const short8v*)&ls[ib][row * LDS_ROW + gq * 8];
                short8v wv = (dd == 0) ? wf[c][0] : (dd <= 6) ? wf[c][1] : wf[c][2];
                // A = x (m=p), B = W (n=o) -> D row=p(quad*4+reg), col=o(lm)
                acc[dd] = __builtin_amdgcn_mfma_f32_16x16x32_bf16(xf, wv, acc[dd], 0, 0, 0);
            }
        }

        // ---- epilogue: residual loads FIRST, then 4 back-to-back stores per
        // row -> each 64B out line completes immediately (no half-dirty
        // eviction + RFO under multi-block churn, the R10 amplification).
        #pragma unroll
        for (int r = 0; r < 4; ++r) {
            const int p = pbase + quad * 4 + r;
            const int o = obase + lm;
            const size_t off = (size_t)p * (C_DIM * D_DIM) + (size_t)o * D_DIM;
            float4v xr[4];
            #pragma unroll
            for (int g = 0; g < 4; ++g)
                xr[g] = *(const float4v*)(x + off + g * 4);
            #pragma unroll
            for (int g = 0; g < 4; ++g) {
                float4v v;
                v.x = acc[g * 4 + 0][r];
                v.y = acc[g * 4 + 1][r];
                v.z = acc[g * 4 + 2][r];
                v.w = acc[g * 4 + 3][r];
                *(float4v*)(out + off + g * 4) = v + xr[g];
            }
        }
    }
}

extern "C" void kernel_launch(void* const* d_in, const int* in_sizes, int n_in,
                              void* d_out, int out_size, void* d_ws, size_t ws_size,
                              hipStream_t stream) {
    const float* x   = (const float*)d_in[0];
    const float* W00 = (const float*)d_in[1];
    const float* W10 = (const float*)d_in[2];
    const float* W11 = (const float*)d_in[3];
    float* out = (float*)d_out;

    const int use_ws = (d_ws != nullptr && ws_size >= WS_NEEDED) ? 1 : 0;
    if (use_ws) {
        hipLaunchKernelGGL(init_w_pack, dim3(96), dim3(256), 0, stream,
                           W00, W10, W11, (uint4v*)d_ws);
    }
    // grid 512: 2 blocks/CU. oh = bid>>8, pg = bid&255 -> the (pg,0)/(pg,1)
    // pair = bids b and b+256 -> same XCD/CU -> shared x tile in L2.
    hipLaunchKernelGGL(glinear_kernel, dim3(512), dim3(512), 0, stream,
                       x, W00, W10, W11, out, (const short8v*)d_ws, use_ws);
}